// Round 2
// baseline (598.067 us; speedup 1.0000x reference)
//
#include <hip/hip_runtime.h>
#include <stdint.h>

// ---------------------------------------------------------------------------
// Types / helpers
// ---------------------------------------------------------------------------
typedef unsigned short u16;
typedef unsigned int   u32;
typedef short bf16x8 __attribute__((ext_vector_type(8)));   // 8 bf16 = 4 VGPRs
typedef float f32x4  __attribute__((ext_vector_type(4)));   // MFMA accumulator

template <int N> struct IC { static constexpr int value = N; };

__device__ __forceinline__ u16 f2bf(float f) {
    union { float f; u32 u; } v; v.f = f;
    u32 u = v.u;
    u32 r = (u + 0x7fffu + ((u >> 16) & 1u)) >> 16;   // RNE
    return (u16)r;
}
__device__ __forceinline__ float bf2f(u16 h) {
    union { u32 u; float f; } v; v.u = ((u32)h) << 16;
    return v.f;
}

// async global->LDS, 16 B per lane.  LDS dest must be wave-uniform base + lane*16.
__device__ __forceinline__ void gload_lds16(const void* g, void* l) {
    __builtin_amdgcn_global_load_lds(
        (__attribute__((address_space(1))) void*)g,
        (__attribute__((address_space(3))) void*)l,
        16, 0, 0);
}

// ---------------------------------------------------------------------------
// fp32 -> bf16 conversion, all three inputs in one launch (block-uniform split)
// ---------------------------------------------------------------------------
__global__ __launch_bounds__(256) void cvt_all(const float4* __restrict__ s1, uint2* __restrict__ d1,
                                               const float4* __restrict__ s2, uint2* __restrict__ d2,
                                               const float4* __restrict__ s3, uint2* __restrict__ d3) {
    const float4* s; uint2* d; int i;
    int b = blockIdx.x;
    if (b < 8192)        { s = s1; d = d1; i = b * 256 + threadIdx.x; }
    else if (b < 32768)  { s = s2; d = d2; i = (b - 8192) * 256 + threadIdx.x; }
    else                 { s = s3; d = d3; i = (b - 32768) * 256 + threadIdx.x; }
    float4 v = s[i];
    uint2 o;
    o.x = (u32)f2bf(v.x) | ((u32)f2bf(v.y) << 16);
    o.y = (u32)f2bf(v.z) | ((u32)f2bf(v.w) << 16);
    d[i] = o;
}

// ---------------------------------------------------------------------------
// 256x256-tile, BK=64, 8-phase NT GEMM: C[M,N] = A[M,K] * B[N,K]^T (bf16 in).
// 8 waves / 512 threads.  LDS 128 KB: double-buffered 256x64 A and B tiles.
// Per phase: 12 ds_read_b128 (XOR-swizzled) + 1 half-tile global_load_lds
// prefetch + barrier + lgkmcnt(0) + 16 MFMA (setprio-wrapped) + barrier.
// Counted vmcnt(4) at phases 3 and 7 (before the closing barrier, so the
// guarantee is cross-wave); vmcnt(0) only at the final iteration's phase 3.
// Swizzle: LDS row r stores global 16B-unit (cp ^ (r&7)) at unit cp; the
// reader XORs its unit index with (r&7).  Kills the 32-way b128 conflict.
// ---------------------------------------------------------------------------
template <typename OUT_T>
__global__ __launch_bounds__(512, 2) void gemm_bt8(const u16* __restrict__ A,
                                                   const u16* __restrict__ B,
                                                   OUT_T* __restrict__ C,
                                                   int M, int N, int K) {
    __shared__ u16 As[2][256 * 64];
    __shared__ u16 Bs[2][256 * 64];

    const int tid  = threadIdx.x;
    const int lane = tid & 63;
    const int wv   = tid >> 6;
    const int row0 = blockIdx.y * 256;
    const int col0 = blockIdx.x * 256;

    const int fr = lane & 15;
    const int fq = lane >> 4;
    const int u0 = (fq ^ (fr & 7)) * 8;   // swizzled element offset, k-slice 0
    const int u1 = u0 ^ 32;               // k-slice 1 (unit ^ 4 -> elems ^ 32)

    const int sr  = tid >> 3;             // staging row within a 64-row group
    const int scp = tid & 7;              // staging 16B unit within the row
    const int sgc = scp ^ (sr & 7);       // swizzled global unit

    const int wrr = (wv >> 2) * 64;       // wave row offset within 128-quadrant
    const int wcc = (wv & 3) * 32;        // wave col offset within 128-quadrant

    f32x4 acc[2][2][4][2];
#pragma unroll
    for (int a = 0; a < 2; ++a)
#pragma unroll
        for (int b = 0; b < 2; ++b)
#pragma unroll
            for (int c = 0; c < 4; ++c)
#pragma unroll
                for (int d = 0; d < 2; ++d) acc[a][b][c][d] = f32x4{0.f, 0.f, 0.f, 0.f};

    auto stageA = [&](int buf, int half, int kt) {
#pragma unroll
        for (int j = 0; j < 2; ++j) {
            int r = j * 64 + sr;
            gload_lds16(A + (size_t)(row0 + half * 128 + r) * K + kt * 64 + sgc * 8,
                        &As[buf][(half * 128 + r) * 64 + scp * 8]);
        }
    };
    auto stageB = [&](int buf, int half, int kt) {
#pragma unroll
        for (int j = 0; j < 2; ++j) {
            int r = j * 64 + sr;
            gload_lds16(B + (size_t)(col0 + half * 128 + r) * K + kt * 64 + sgc * 8,
                        &Bs[buf][(half * 128 + r) * 64 + scp * 8]);
        }
    };

    // One phase: quadrant (MQ,NQ) of C from buffer BUF, K=64.
    // vmEnd: -1 none, 4 -> s_waitcnt vmcnt(4), 0 -> vmcnt(0); placed before
    // the closing barrier so the landing guarantee is block-wide.
    auto phase = [&](auto BUFc, auto MQc, auto NQc, int vmEnd, auto&& stg) {
        constexpr int BUF = decltype(BUFc)::value;
        constexpr int MQ  = decltype(MQc)::value;
        constexpr int NQ  = decltype(NQc)::value;
        const u16* as_ = &As[BUF][(MQ * 128 + wrr + fr) * 64];
        const u16* bs_ = &Bs[BUF][(NQ * 128 + wcc + fr) * 64];
        bf16x8 af[4][2], bfv[2][2];
#pragma unroll
        for (int im = 0; im < 4; ++im) {
            af[im][0] = *(const bf16x8*)&as_[im * 1024 + u0];
            af[im][1] = *(const bf16x8*)&as_[im * 1024 + u1];
        }
#pragma unroll
        for (int in = 0; in < 2; ++in) {
            bfv[in][0] = *(const bf16x8*)&bs_[in * 1024 + u0];
            bfv[in][1] = *(const bf16x8*)&bs_[in * 1024 + u1];
        }
        stg();
        __builtin_amdgcn_s_barrier();
        asm volatile("s_waitcnt lgkmcnt(0)" ::: "memory");
        __builtin_amdgcn_sched_barrier(0);
        __builtin_amdgcn_s_setprio(1);
#pragma unroll
        for (int im = 0; im < 4; ++im)
#pragma unroll
            for (int in = 0; in < 2; ++in) {
                acc[MQ][NQ][im][in] = __builtin_amdgcn_mfma_f32_16x16x32_bf16(
                    af[im][0], bfv[in][0], acc[MQ][NQ][im][in], 0, 0, 0);
                acc[MQ][NQ][im][in] = __builtin_amdgcn_mfma_f32_16x16x32_bf16(
                    af[im][1], bfv[in][1], acc[MQ][NQ][im][in], 0, 0, 0);
            }
        __builtin_amdgcn_s_setprio(0);
        if (vmEnd == 4)      asm volatile("s_waitcnt vmcnt(4)" ::: "memory");
        else if (vmEnd == 0) asm volatile("s_waitcnt vmcnt(0)" ::: "memory");
        __builtin_amdgcn_s_barrier();
    };

    const int nkt = K >> 6;        // 64-wide K-tiles
    const int nit = nkt >> 1;      // 2 K-tiles per iteration

    // prologue: tile0 (4 halves) -> buf0; tile1 A0,B0 -> buf1; wait+barrier
    stageA(0, 0, 0); stageB(0, 0, 0); stageA(0, 1, 0); stageB(0, 1, 0);
    stageA(1, 0, 1); stageB(1, 0, 1);
    asm volatile("s_waitcnt vmcnt(4)" ::: "memory");
    __builtin_amdgcn_s_barrier();

    for (int it = 0; it < nit; ++it) {
        const int t1 = 2 * it + 1;     // phases 4-7 tile (buf1)
        const int t2 = 2 * it + 2;     // next even tile  (buf0)
        const int t3 = t2 + 1;         // next odd tile   (buf1)
        const bool h2 = t2 < nkt, h3 = t3 < nkt;
        // phases 0-3: buf0 (tile 2it); stage t1's A1,B1 then t2's A0,B0
        phase(IC<0>{}, IC<0>{}, IC<0>{}, -1,          [&] { stageA(1, 1, t1); });
        phase(IC<0>{}, IC<0>{}, IC<1>{}, -1,          [&] { stageB(1, 1, t1); });
        phase(IC<0>{}, IC<1>{}, IC<0>{}, -1,          [&] { if (h2) stageA(0, 0, t2); });
        phase(IC<0>{}, IC<1>{}, IC<1>{}, h2 ? 4 : 0,  [&] { if (h2) stageB(0, 0, t2); });
        // phases 4-7: buf1 (tile 2it+1); stage t2's A1,B1 then t3's A0,B0
        phase(IC<1>{}, IC<0>{}, IC<0>{}, -1,          [&] { if (h2) stageA(0, 1, t2); });
        phase(IC<1>{}, IC<0>{}, IC<1>{}, -1,          [&] { if (h2) stageB(0, 1, t2); });
        phase(IC<1>{}, IC<1>{}, IC<0>{}, -1,          [&] { if (h3) stageA(1, 0, t3); });
        phase(IC<1>{}, IC<1>{}, IC<1>{}, 4,           [&] { if (h3) stageB(1, 0, t3); });
    }

    // epilogue: C write
    const int orow = (lane >> 4) * 4;
    const int ocol = lane & 15;
#pragma unroll
    for (int mq = 0; mq < 2; ++mq)
#pragma unroll
        for (int nq = 0; nq < 2; ++nq)
#pragma unroll
            for (int im = 0; im < 4; ++im)
#pragma unroll
                for (int in = 0; in < 2; ++in)
#pragma unroll
                    for (int r = 0; r < 4; ++r) {
                        int mm = row0 + mq * 128 + wrr + im * 16 + orow + r;
                        int nn = col0 + nq * 128 + wcc + in * 16 + ocol;
                        float v = acc[mq][nq][im][in][r];
                        if constexpr (sizeof(OUT_T) == 2)
                            C[(size_t)mm * N + nn] = (OUT_T)f2bf(v);
                        else
                            C[(size_t)mm * N + nn] = (OUT_T)v;
                    }
}

// ---------------------------------------------------------------------------
// prep_kv: blocks [0,4096) apply RoPE to K -> Kb(8,S,128);
//          blocks [4096,5120) transpose V -> Vt[8][128][2048].   (unchanged)
// ---------------------------------------------------------------------------
__global__ __launch_bounds__(256) void prep_kv(const u16* __restrict__ qkv,
                                               u16* __restrict__ Kb,
                                               u16* __restrict__ Vt) {
    if (blockIdx.x < 4096) {
        int id = blockIdx.x * 256 + threadIdx.x;
        int d  = id & 63;
        int t  = id >> 6;
        int kh = t & 7;
        int s  = t >> 3;
        const size_t rowbase = (size_t)s * 6144 + 4096;
        float inv = __expf(-(float)d * (9.210340371976184f / 64.0f));
        float ang = (float)s * inv;
        float cs, sn; __sincosf(ang, &sn, &cs);
        float x1 = bf2f(qkv[rowbase + kh * 128 + d]);
        float x2 = bf2f(qkv[rowbase + kh * 128 + d + 64]);
        size_t o = ((size_t)kh * 2048 + s) * 128 + d;
        Kb[o]      = f2bf(x1 * cs - x2 * sn);
        Kb[o + 64] = f2bf(x1 * sn + x2 * cs);
    } else {
        int id = (blockIdx.x - 4096) * 256 + threadIdx.x;
        int s8 = id & 255;
        int d  = (id >> 8) & 127;
        int vh = id >> 15;
        u16 tmp[8];
#pragma unroll
        for (int j = 0; j < 8; ++j)
            tmp[j] = qkv[(size_t)(s8 * 8 + j) * 6144 + 5120 + vh * 128 + d];
        *(uint4*)(Vt + ((size_t)vh * 128 + d) * 2048 + s8 * 8) = *(uint4*)tmp;
    }
}

// ---------------------------------------------------------------------------
// Softmax + in-register P transpose (verified round 1).
// ---------------------------------------------------------------------------
__device__ __forceinline__ void softmax_pack(f32x4 s[4], bool diag, int w, int m, int quad,
                                             float sl2e, float& lsum, bf16x8 af[2]) {
#pragma unroll
    for (int nt = 0; nt < 4; ++nt)
#pragma unroll
        for (int r = 0; r < 4; ++r) {
            float p = __builtin_amdgcn_exp2f(s[nt][r] * sl2e);
            if (diag && (nt * 16 + quad * 4 + r > w * 16 + m)) p = 0.f;
            s[nt][r] = p;
            lsum += p;
        }
#pragma unroll
    for (int kk2 = 0; kk2 < 2; ++kk2)
#pragma unroll
        for (int ws = 0; ws < 2; ++ws) {
            u32 a, b;
            asm("v_cvt_pk_bf16_f32 %0, %1, %2"
                : "=v"(a) : "v"(s[2 * kk2][2 * ws]), "v"(s[2 * kk2][2 * ws + 1]));
            asm("v_cvt_pk_bf16_f32 %0, %1, %2"
                : "=v"(b) : "v"(s[2 * kk2 + 1][2 * ws]), "v"(s[2 * kk2 + 1][2 * ws + 1]));
            asm("v_permlane32_swap_b32 %0, %1" : "+v"(a), "+v"(b));
            asm("v_permlane16_swap_b32 %0, %1" : "+v"(a), "+v"(b));
            ((u32*)&af[kk2])[ws]     = a;
            ((u32*)&af[kk2])[ws + 2] = b;
        }
}

// ---------------------------------------------------------------------------
// One (or two, fused) QK^T -> exp2 -> PV passes over a staged 64-row K/V tile.
// ---------------------------------------------------------------------------
template <bool TWO>
__device__ __forceinline__ void attn_pass2(const bf16x8 qfA[4], const bf16x8 qfB[4],
                                           f32x4 accA[8], f32x4 accB[8],
                                           float& lA, float& lB,
                                           const u16* Ks, const u16* Vs,
                                           int w, int m, int quad,
                                           bool diagA, bool diagB, float sl2e) {
    f32x4 sA[4], sB[4];
#pragma unroll
    for (int nt = 0; nt < 4; ++nt) {
        sA[nt] = f32x4{0.f, 0.f, 0.f, 0.f};
        sB[nt] = f32x4{0.f, 0.f, 0.f, 0.f};
    }

    __builtin_amdgcn_s_setprio(1);
#pragma unroll
    for (int kk = 0; kk < 4; ++kk)
#pragma unroll
        for (int nt = 0; nt < 4; ++nt) {
            int pos = (kk * 4 + quad) ^ (m & 7);
            bf16x8 b = *(const bf16x8*)&Ks[(nt * 16 + m) * 128 + pos * 8];
            sB[nt] = __builtin_amdgcn_mfma_f32_16x16x32_bf16(b, qfB[kk], sB[nt], 0, 0, 0);
            if constexpr (TWO)
                sA[nt] = __builtin_amdgcn_mfma_f32_16x16x32_bf16(b, qfA[kk], sA[nt], 0, 0, 0);
        }
    __builtin_amdgcn_s_setprio(0);

    bf16x8 afA[2], afB[2];
    softmax_pack(sB, diagB, w, m, quad, sl2e, lB, afB);
    if constexpr (TWO) softmax_pack(sA, diagA, w, m, quad, sl2e, lA, afA);

    __builtin_amdgcn_s_setprio(1);
#pragma unroll
    for (int kk2 = 0; kk2 < 2; ++kk2)
#pragma unroll
        for (int nt = 0; nt < 8; ++nt) {
            int pos = (kk2 * 4 + quad) ^ (m & 7);
            bf16x8 b = *(const bf16x8*)&Vs[(nt * 16 + m) * 64 + pos * 8];
            accB[nt] = __builtin_amdgcn_mfma_f32_16x16x32_bf16(afB[kk2], b, accB[nt], 0, 0, 0);
            if constexpr (TWO)
                accA[nt] = __builtin_amdgcn_mfma_f32_16x16x32_bf16(afA[kk2], b, accA[nt], 0, 0, 0);
        }
    __builtin_amdgcn_s_setprio(0);
}

// ---------------------------------------------------------------------------
// MFMA flash attention (unchanged from round 1).
// ---------------------------------------------------------------------------
__global__ __launch_bounds__(256, 2) void attn_mfma(const u16* __restrict__ qkv,
                                                    const u16* __restrict__ Kb,
                                                    const u16* __restrict__ Vt,
                                                    u16* __restrict__ ctx) {
    __shared__ u16 Ks[2][64 * 128];
    __shared__ u16 Vs[2][128 * 64];

    const int tid  = threadIdx.x;
    const int lane = tid & 63;
    const int w    = tid >> 6;
    const int m    = lane & 15;
    const int quad = lane >> 4;
    const int h    = blockIdx.y;
    const int kh   = h >> 2;            // GQA groups = 4
    const int qtA  = blockIdx.x;        // 0..15
    const int qtB  = 31 - qtA;          // 16..31

    const u16* Ktile0 = Kb + (size_t)kh * 2048 * 128;
    const u16* Vtile0 = Vt + (size_t)kh * 128 * 2048;
    const float sl2e = 0.08838834764831845f * 1.4426950408889634f; // scale*log2(e)

    auto stage = [&](int buf, int kt) {
        const u16* Kt = Ktile0 + (size_t)kt * 64 * 128;
#pragma unroll
        for (int i = 0; i < 4; ++i) {
            int slot = i * 256 + tid;
            int row = slot >> 4, cp = slot & 15;
            int gc = cp ^ (row & 7);             // swizzle on global side
            gload_lds16(Kt + row * 128 + gc * 8, &Ks[buf][slot * 8]);
        }
        const u16* Vtt = Vtile0 + kt * 64;
#pragma unroll
        for (int i = 0; i < 4; ++i) {
            int slot = i * 256 + tid;
            int row = slot >> 3, cp = slot & 7;
            int gc = cp ^ (row & 7);
            gload_lds16(Vtt + (size_t)row * 2048 + gc * 8, &Vs[buf][slot * 8]);
        }
    };

    // ---- load Q rows for both q-tiles straight from qkv, RoPE in registers
    bf16x8 qa[4], qb[4];
#pragma unroll
    for (int which = 0; which < 2; ++which) {
        const int qt = which ? qtB : qtA;
        const int s  = qt * 64 + w * 16 + m;
        bf16x8 raw[4];
        const u16* qp = qkv + (size_t)s * 6144 + h * 128 + quad * 8;
#pragma unroll
        for (int kk = 0; kk < 4; ++kk)
            raw[kk] = *(const bf16x8*)(qp + kk * 32);
        bf16x8* dst = which ? qb : qa;
#pragma unroll
        for (int half = 0; half < 2; ++half)
#pragma unroll
            for (int j = 0; j < 8; ++j) {
                int d = half * 32 + quad * 8 + j;
                float inv = __expf(-(float)d * (9.210340371976184f / 64.0f));
                float ang = (float)s * inv;
                float cs, sn; __sincosf(ang, &sn, &cs);
                float x1 = bf2f(((const u16*)&raw[half])[j]);
                float x2 = bf2f(((const u16*)&raw[half + 2])[j]);
                ((u16*)&dst[half])[j]     = f2bf(x1 * cs - x2 * sn);
                ((u16*)&dst[half + 2])[j] = f2bf(x1 * sn + x2 * cs);
            }
    }

    f32x4 accA[8], accB[8];
#pragma unroll
    for (int i = 0; i < 8; ++i) { accA[i] = f32x4{0.f, 0.f, 0.f, 0.f}; accB[i] = f32x4{0.f, 0.f, 0.f, 0.f}; }
    float lA = 0.f, lB = 0.f;

    stage(0, 0);
    for (int kt = 0; kt <= qtB; ++kt) {
        __syncthreads();                       // drains *previous* prefetch only
        if (kt < qtB) stage((kt + 1) & 1, kt + 1);   // fly during this tile's math

        const u16* ks = Ks[kt & 1];
        const u16* vs = Vs[kt & 1];
        if (kt <= qtA)
            attn_pass2<true >(qa, qb, accA, accB, lA, lB, ks, vs, w, m, quad,
                              kt == qtA, false, sl2e);
        else
            attn_pass2<false>(qa, qb, accA, accB, lA, lB, ks, vs, w, m, quad,
                              false, kt == qtB, sl2e);
    }

    // ---- epilogues
#pragma unroll
    for (int which = 0; which < 2; ++which) {
        const int qt  = which ? qtB : qtA;
        f32x4*   acc  = which ? accB : accA;
        float    l    = which ? lB   : lA;
        l += __shfl_xor(l, 16);
        l += __shfl_xor(l, 32);
        float linv[4];
#pragma unroll
        for (int r = 0; r < 4; ++r)
            linv[r] = 1.f / __shfl(l, quad * 4 + r);
#pragma unroll
        for (int r = 0; r < 4; ++r) {
            size_t rowg = (size_t)(qt * 64 + w * 16 + quad * 4 + r);
#pragma unroll
            for (int nt = 0; nt < 8; ++nt)
                ctx[rowg * 4096 + h * 128 + nt * 16 + m] = f2bf(acc[nt][r] * linv[r]);
        }
    }
}

// ---------------------------------------------------------------------------
// Launcher
// ---------------------------------------------------------------------------
extern "C" void kernel_launch(void* const* d_in, const int* in_sizes, int n_in,
                              void* d_out, int out_size, void* d_ws, size_t ws_size,
                              hipStream_t stream) {
    const float* hs   = (const float*)d_in[0];   // (1,2048,4096)
    const float* wqkv = (const float*)d_in[1];   // (6144,4096)
    const float* wo   = (const float*)d_in[2];   // (4096,4096)
    float* out = (float*)d_out;                  // (1,2048,4096) fp32

    char* ws = (char*)d_ws;
    u16* hA  = (u16*)ws;  ws += (size_t)2048 * 4096 * 2;   // hidden bf16
    u16* wQ  = (u16*)ws;  ws += (size_t)6144 * 4096 * 2;   // Wqkv bf16
    u16* wO  = (u16*)ws;  ws += (size_t)4096 * 4096 * 2;   // Wo bf16
    u16* qkv = (u16*)ws;  ws += (size_t)2048 * 6144 * 2;   // qkv bf16
    u16* Kb  = (u16*)ws;  ws += (size_t)8 * 2048 * 128 * 2; // K, RoPE'd
    u16* Vt  = (u16*)ws;  ws += (size_t)8 * 128 * 2048 * 2; // V transposed
    u16* ctx = (u16*)ws;  ws += (size_t)2048 * 4096 * 2;   // attention output

    // all three fp32->bf16 conversions in one launch
    cvt_all<<<49152, 256, 0, stream>>>((const float4*)hs,   (uint2*)hA,
                                       (const float4*)wqkv, (uint2*)wQ,
                                       (const float4*)wo,   (uint2*)wO);

    // qkv = hidden @ Wqkv^T   (M=2048, N=6144, K=4096): 24x8 = 192 blocks
    gemm_bt8<u16><<<dim3(24, 8), 512, 0, stream>>>(hA, wQ, qkv, 2048, 6144, 4096);

    // K RoPE + V transpose in one launch
    prep_kv<<<5120, 256, 0, stream>>>(qkv, Kb, Vt);

    // balanced, merged-pass, register-P flash attention
    attn_mfma<<<dim3(16, 32), 256, 0, stream>>>(qkv, Kb, Vt, ctx);

    // out = ctx @ Wo^T   (M=2048, N=4096, K=4096): 16x8 = 128 blocks
    gemm_bt8<float><<<dim3(16, 8), 512, 0, stream>>>(ctx, wO, out, 2048, 4096, 4096);
}

// Round 3
// 541.993 us; speedup vs baseline: 1.1035x; 1.1035x over previous
//
#include <hip/hip_runtime.h>
#include <stdint.h>

// ---------------------------------------------------------------------------
// Types / helpers
// ---------------------------------------------------------------------------
typedef unsigned short u16;
typedef unsigned int   u32;
typedef short bf16x8 __attribute__((ext_vector_type(8)));   // 8 bf16 = 4 VGPRs
typedef float f32x4  __attribute__((ext_vector_type(4)));   // MFMA accumulator

template <int N> struct IC { static constexpr int value = N; };

__device__ __forceinline__ u16 f2bf(float f) {
    union { float f; u32 u; } v; v.f = f;
    u32 u = v.u;
    u32 r = (u + 0x7fffu + ((u >> 16) & 1u)) >> 16;   // RNE
    return (u16)r;
}
__device__ __forceinline__ float bf2f(u16 h) {
    union { u32 u; float f; } v; v.u = ((u32)h) << 16;
    return v.f;
}

// async global->LDS, 16 B per lane.  LDS dest must be wave-uniform base + lane*16.
__device__ __forceinline__ void gload_lds16(const void* g, void* l) {
    __builtin_amdgcn_global_load_lds(
        (__attribute__((address_space(1))) void*)g,
        (__attribute__((address_space(3))) void*)l,
        16, 0, 0);
}

// ---------------------------------------------------------------------------
// fp32 -> bf16 conversion, all three inputs in one launch (block-uniform split)
// ---------------------------------------------------------------------------
__global__ __launch_bounds__(256) void cvt_all(const float4* __restrict__ s1, uint2* __restrict__ d1,
                                               const float4* __restrict__ s2, uint2* __restrict__ d2,
                                               const float4* __restrict__ s3, uint2* __restrict__ d3) {
    const float4* s; uint2* d; int i;
    int b = blockIdx.x;
    if (b < 8192)        { s = s1; d = d1; i = b * 256 + threadIdx.x; }
    else if (b < 32768)  { s = s2; d = d2; i = (b - 8192) * 256 + threadIdx.x; }
    else                 { s = s3; d = d3; i = (b - 32768) * 256 + threadIdx.x; }
    float4 v = s[i];
    uint2 o;
    o.x = (u32)f2bf(v.x) | ((u32)f2bf(v.y) << 16);
    o.y = (u32)f2bf(v.z) | ((u32)f2bf(v.w) << 16);
    d[i] = o;
}

// ---------------------------------------------------------------------------
// 256x256-tile, BK=64, 8-phase NT GEMM: C[M,N] = A[M,K] * B[N,K]^T (bf16 in).
// 8 waves / 512 threads.  LDS 128 KB: double-buffered 256x64 A and B tiles.
// Fragment REUSE across phases (m201 template): per K-tile the 4 phases read
// {A-half0 + B-set0 : 12}, {B-set1 : 4}, {A-half1 : 8}, {none : 0} ds_read_b128
// -- 24 reads/K-tile instead of 48.  Stage/vmcnt schedule identical to the
// verified round-2 version.  1D grid with bijective XCD swizzle.
// ---------------------------------------------------------------------------
template <typename OUT_T>
__global__ __launch_bounds__(512, 2) void gemm_bt8(const u16* __restrict__ A,
                                                   const u16* __restrict__ B,
                                                   OUT_T* __restrict__ C,
                                                   int M, int N, int K) {
    __shared__ u16 As[2][256 * 64];
    __shared__ u16 Bs[2][256 * 64];

    const int tid  = threadIdx.x;
    const int lane = tid & 63;
    const int wv   = tid >> 6;

    // bijective XCD swizzle (nwg % 8 == 0 for all our launches): each XCD
    // processes a contiguous chunk = full rows of col-tiles -> A-panel L2 reuse.
    const int nwg = gridDim.x;
    const int nx  = N >> 8;
    const int swz = ((int)blockIdx.x & 7) * (nwg >> 3) + ((int)blockIdx.x >> 3);
    const int row0 = (swz / nx) * 256;
    const int col0 = (swz % nx) * 256;

    const int fr = lane & 15;
    const int fq = lane >> 4;
    const int u0 = (fq ^ (fr & 7)) * 8;   // swizzled element offset, k-slice 0
    const int u1 = u0 ^ 32;               // k-slice 1 (unit ^ 4 -> elems ^ 32)

    const int sr  = tid >> 3;             // staging row within a 64-row group
    const int scp = tid & 7;              // staging 16B unit within the row
    const int sgc = scp ^ (sr & 7);       // swizzled global unit

    const int wrr = (wv >> 2) * 64;       // wave row offset within 128-quadrant
    const int wcc = (wv & 3) * 32;        // wave col offset within 128-quadrant

    f32x4 acc[2][2][4][2];
#pragma unroll
    for (int a = 0; a < 2; ++a)
#pragma unroll
        for (int b = 0; b < 2; ++b)
#pragma unroll
            for (int c = 0; c < 4; ++c)
#pragma unroll
                for (int d = 0; d < 2; ++d) acc[a][b][c][d] = f32x4{0.f, 0.f, 0.f, 0.f};

    // live fragment state (reused across phases)
    bf16x8 af[4][2];        // current A half (4 m-tiles x 2 k-slices)
    bf16x8 bfv[2][2][2];    // [n-set][2 n-tiles][2 k-slices] -- both sets live

    auto readA = [&](int buf, int mq) {
        const u16* as_ = &As[buf][(mq * 128 + wrr + fr) * 64];
#pragma unroll
        for (int im = 0; im < 4; ++im) {
            af[im][0] = *(const bf16x8*)&as_[im * 1024 + u0];
            af[im][1] = *(const bf16x8*)&as_[im * 1024 + u1];
        }
    };
    auto readB = [&](int buf, auto NQc) {
        constexpr int NQ = decltype(NQc)::value;
        const u16* bs_ = &Bs[buf][(NQ * 128 + wcc + fr) * 64];
#pragma unroll
        for (int in = 0; in < 2; ++in) {
            bfv[NQ][in][0] = *(const bf16x8*)&bs_[in * 1024 + u0];
            bfv[NQ][in][1] = *(const bf16x8*)&bs_[in * 1024 + u1];
        }
    };
    auto mfma16 = [&](auto MQc, auto NQc) {
        constexpr int MQ = decltype(MQc)::value;
        constexpr int NQ = decltype(NQc)::value;
        __builtin_amdgcn_s_setprio(1);
#pragma unroll
        for (int im = 0; im < 4; ++im)
#pragma unroll
            for (int in = 0; in < 2; ++in) {
                acc[MQ][NQ][im][in] = __builtin_amdgcn_mfma_f32_16x16x32_bf16(
                    af[im][0], bfv[NQ][in][0], acc[MQ][NQ][im][in], 0, 0, 0);
                acc[MQ][NQ][im][in] = __builtin_amdgcn_mfma_f32_16x16x32_bf16(
                    af[im][1], bfv[NQ][in][1], acc[MQ][NQ][im][in], 0, 0, 0);
            }
        __builtin_amdgcn_s_setprio(0);
    };

    auto stageA = [&](int buf, int half, int kt) {
#pragma unroll
        for (int j = 0; j < 2; ++j) {
            int r = j * 64 + sr;
            gload_lds16(A + (size_t)(row0 + half * 128 + r) * K + kt * 64 + sgc * 8,
                        &As[buf][(half * 128 + r) * 64 + scp * 8]);
        }
    };
    auto stageB = [&](int buf, int half, int kt) {
#pragma unroll
        for (int j = 0; j < 2; ++j) {
            int r = j * 64 + sr;
            gload_lds16(B + (size_t)(col0 + half * 128 + r) * K + kt * 64 + sgc * 8,
                        &Bs[buf][(half * 128 + r) * 64 + scp * 8]);
        }
    };

    // One phase.  vmEnd: -1 none, 4 -> vmcnt(4), 0 -> vmcnt(0); placed before
    // the closing barrier so the landing guarantee is block-wide.
    auto phase = [&](auto&& rds, auto&& stg, auto MQc, auto NQc, int vmEnd) {
        rds();
        stg();
        __builtin_amdgcn_s_barrier();
        asm volatile("s_waitcnt lgkmcnt(0)" ::: "memory");
        __builtin_amdgcn_sched_barrier(0);
        mfma16(MQc, NQc);
        if (vmEnd == 4)      asm volatile("s_waitcnt vmcnt(4)" ::: "memory");
        else if (vmEnd == 0) asm volatile("s_waitcnt vmcnt(0)" ::: "memory");
        __builtin_amdgcn_s_barrier();
    };

    const int nkt = K >> 6;        // 64-wide K-tiles
    const int nit = nkt >> 1;      // 2 K-tiles per iteration

    // prologue: tile0 (4 halves) -> buf0; tile1 A0,B0 -> buf1; wait+barrier
    stageA(0, 0, 0); stageB(0, 0, 0); stageA(0, 1, 0); stageB(0, 1, 0);
    stageA(1, 0, 1); stageB(1, 0, 1);
    asm volatile("s_waitcnt vmcnt(4)" ::: "memory");
    __builtin_amdgcn_s_barrier();

    for (int it = 0; it < nit; ++it) {
        const int t1 = 2 * it + 1;     // phases 4-7 tile (buf1)
        const int t2 = 2 * it + 2;     // next even tile  (buf0)
        const int t3 = t2 + 1;         // next odd tile   (buf1)
        const bool h2 = t2 < nkt, h3 = t3 < nkt;
        // phases 0-3: buf0 (tile 2it)
        phase([&] { readA(0, 0); readB(0, IC<0>{}); }, [&] { stageA(1, 1, t1); },
              IC<0>{}, IC<0>{}, -1);
        phase([&] { readB(0, IC<1>{}); },              [&] { stageB(1, 1, t1); },
              IC<0>{}, IC<1>{}, -1);
        phase([&] { readA(0, 1); },                    [&] { if (h2) stageA(0, 0, t2); },
              IC<1>{}, IC<0>{}, -1);
        phase([&] {},                                  [&] { if (h2) stageB(0, 0, t2); },
              IC<1>{}, IC<1>{}, h2 ? 4 : 0);
        // phases 4-7: buf1 (tile 2it+1)
        phase([&] { readA(1, 0); readB(1, IC<0>{}); }, [&] { if (h2) stageA(0, 1, t2); },
              IC<0>{}, IC<0>{}, -1);
        phase([&] { readB(1, IC<1>{}); },              [&] { if (h2) stageB(0, 1, t2); },
              IC<0>{}, IC<1>{}, -1);
        phase([&] { readA(1, 1); },                    [&] { if (h3) stageA(1, 0, t3); },
              IC<1>{}, IC<0>{}, -1);
        phase([&] {},                                  [&] { if (h3) stageB(1, 0, t3); },
              IC<1>{}, IC<1>{}, 4);
    }

    // epilogue: C write
    const int orow = (lane >> 4) * 4;
    const int ocol = lane & 15;
#pragma unroll
    for (int mq = 0; mq < 2; ++mq)
#pragma unroll
        for (int nq = 0; nq < 2; ++nq)
#pragma unroll
            for (int im = 0; im < 4; ++im)
#pragma unroll
                for (int in = 0; in < 2; ++in)
#pragma unroll
                    for (int r = 0; r < 4; ++r) {
                        int mm = row0 + mq * 128 + wrr + im * 16 + orow + r;
                        int nn = col0 + nq * 128 + wcc + in * 16 + ocol;
                        float v = acc[mq][nq][im][in][r];
                        if constexpr (sizeof(OUT_T) == 2)
                            C[(size_t)mm * N + nn] = (OUT_T)f2bf(v);
                        else
                            C[(size_t)mm * N + nn] = (OUT_T)v;
                    }
}

// ---------------------------------------------------------------------------
// prep_kv: blocks [0,4096) apply RoPE to K -> Kb(8,S,128);
//          blocks [4096,5120) transpose V -> Vt[8][128][2048].   (unchanged)
// ---------------------------------------------------------------------------
__global__ __launch_bounds__(256) void prep_kv(const u16* __restrict__ qkv,
                                               u16* __restrict__ Kb,
                                               u16* __restrict__ Vt) {
    if (blockIdx.x < 4096) {
        int id = blockIdx.x * 256 + threadIdx.x;
        int d  = id & 63;
        int t  = id >> 6;
        int kh = t & 7;
        int s  = t >> 3;
        const size_t rowbase = (size_t)s * 6144 + 4096;
        float inv = __expf(-(float)d * (9.210340371976184f / 64.0f));
        float ang = (float)s * inv;
        float cs, sn; __sincosf(ang, &sn, &cs);
        float x1 = bf2f(qkv[rowbase + kh * 128 + d]);
        float x2 = bf2f(qkv[rowbase + kh * 128 + d + 64]);
        size_t o = ((size_t)kh * 2048 + s) * 128 + d;
        Kb[o]      = f2bf(x1 * cs - x2 * sn);
        Kb[o + 64] = f2bf(x1 * sn + x2 * cs);
    } else {
        int id = (blockIdx.x - 4096) * 256 + threadIdx.x;
        int s8 = id & 255;
        int d  = (id >> 8) & 127;
        int vh = id >> 15;
        u16 tmp[8];
#pragma unroll
        for (int j = 0; j < 8; ++j)
            tmp[j] = qkv[(size_t)(s8 * 8 + j) * 6144 + 5120 + vh * 128 + d];
        *(uint4*)(Vt + ((size_t)vh * 128 + d) * 2048 + s8 * 8) = *(uint4*)tmp;
    }
}

// ---------------------------------------------------------------------------
// Softmax + in-register P transpose (verified round 1).
// ---------------------------------------------------------------------------
__device__ __forceinline__ void softmax_pack(f32x4 s[4], bool diag, int w, int m, int quad,
                                             float sl2e, float& lsum, bf16x8 af[2]) {
#pragma unroll
    for (int nt = 0; nt < 4; ++nt)
#pragma unroll
        for (int r = 0; r < 4; ++r) {
            float p = __builtin_amdgcn_exp2f(s[nt][r] * sl2e);
            if (diag && (nt * 16 + quad * 4 + r > w * 16 + m)) p = 0.f;
            s[nt][r] = p;
            lsum += p;
        }
#pragma unroll
    for (int kk2 = 0; kk2 < 2; ++kk2)
#pragma unroll
        for (int ws = 0; ws < 2; ++ws) {
            u32 a, b;
            asm("v_cvt_pk_bf16_f32 %0, %1, %2"
                : "=v"(a) : "v"(s[2 * kk2][2 * ws]), "v"(s[2 * kk2][2 * ws + 1]));
            asm("v_cvt_pk_bf16_f32 %0, %1, %2"
                : "=v"(b) : "v"(s[2 * kk2 + 1][2 * ws]), "v"(s[2 * kk2 + 1][2 * ws + 1]));
            asm("v_permlane32_swap_b32 %0, %1" : "+v"(a), "+v"(b));
            asm("v_permlane16_swap_b32 %0, %1" : "+v"(a), "+v"(b));
            ((u32*)&af[kk2])[ws]     = a;
            ((u32*)&af[kk2])[ws + 2] = b;
        }
}

// ---------------------------------------------------------------------------
// One (or two, fused) QK^T -> exp2 -> PV passes over a staged 64-row K/V tile.
// ---------------------------------------------------------------------------
template <bool TWO>
__device__ __forceinline__ void attn_pass2(const bf16x8 qfA[4], const bf16x8 qfB[4],
                                           f32x4 accA[8], f32x4 accB[8],
                                           float& lA, float& lB,
                                           const u16* Ks, const u16* Vs,
                                           int w, int m, int quad,
                                           bool diagA, bool diagB, float sl2e) {
    f32x4 sA[4], sB[4];
#pragma unroll
    for (int nt = 0; nt < 4; ++nt) {
        sA[nt] = f32x4{0.f, 0.f, 0.f, 0.f};
        sB[nt] = f32x4{0.f, 0.f, 0.f, 0.f};
    }

    __builtin_amdgcn_s_setprio(1);
#pragma unroll
    for (int kk = 0; kk < 4; ++kk)
#pragma unroll
        for (int nt = 0; nt < 4; ++nt) {
            int pos = (kk * 4 + quad) ^ (m & 7);
            bf16x8 b = *(const bf16x8*)&Ks[(nt * 16 + m) * 128 + pos * 8];
            sB[nt] = __builtin_amdgcn_mfma_f32_16x16x32_bf16(b, qfB[kk], sB[nt], 0, 0, 0);
            if constexpr (TWO)
                sA[nt] = __builtin_amdgcn_mfma_f32_16x16x32_bf16(b, qfA[kk], sA[nt], 0, 0, 0);
        }
    __builtin_amdgcn_s_setprio(0);

    bf16x8 afA[2], afB[2];
    softmax_pack(sB, diagB, w, m, quad, sl2e, lB, afB);
    if constexpr (TWO) softmax_pack(sA, diagA, w, m, quad, sl2e, lA, afA);

    __builtin_amdgcn_s_setprio(1);
#pragma unroll
    for (int kk2 = 0; kk2 < 2; ++kk2)
#pragma unroll
        for (int nt = 0; nt < 8; ++nt) {
            int pos = (kk2 * 4 + quad) ^ (m & 7);
            bf16x8 b = *(const bf16x8*)&Vs[(nt * 16 + m) * 64 + pos * 8];
            accB[nt] = __builtin_amdgcn_mfma_f32_16x16x32_bf16(afB[kk2], b, accB[nt], 0, 0, 0);
            if constexpr (TWO)
                accA[nt] = __builtin_amdgcn_mfma_f32_16x16x32_bf16(afA[kk2], b, accA[nt], 0, 0, 0);
        }
    __builtin_amdgcn_s_setprio(0);
}

// ---------------------------------------------------------------------------
// MFMA flash attention (unchanged).
// ---------------------------------------------------------------------------
__global__ __launch_bounds__(256, 2) void attn_mfma(const u16* __restrict__ qkv,
                                                    const u16* __restrict__ Kb,
                                                    const u16* __restrict__ Vt,
                                                    u16* __restrict__ ctx) {
    __shared__ u16 Ks[2][64 * 128];
    __shared__ u16 Vs[2][128 * 64];

    const int tid  = threadIdx.x;
    const int lane = tid & 63;
    const int w    = tid >> 6;
    const int m    = lane & 15;
    const int quad = lane >> 4;
    const int h    = blockIdx.y;
    const int kh   = h >> 2;            // GQA groups = 4
    const int qtA  = blockIdx.x;        // 0..15
    const int qtB  = 31 - qtA;          // 16..31

    const u16* Ktile0 = Kb + (size_t)kh * 2048 * 128;
    const u16* Vtile0 = Vt + (size_t)kh * 128 * 2048;
    const float sl2e = 0.08838834764831845f * 1.4426950408889634f; // scale*log2(e)

    auto stage = [&](int buf, int kt) {
        const u16* Kt = Ktile0 + (size_t)kt * 64 * 128;
#pragma unroll
        for (int i = 0; i < 4; ++i) {
            int slot = i * 256 + tid;
            int row = slot >> 4, cp = slot & 15;
            int gc = cp ^ (row & 7);             // swizzle on global side
            gload_lds16(Kt + row * 128 + gc * 8, &Ks[buf][slot * 8]);
        }
        const u16* Vtt = Vtile0 + kt * 64;
#pragma unroll
        for (int i = 0; i < 4; ++i) {
            int slot = i * 256 + tid;
            int row = slot >> 3, cp = slot & 7;
            int gc = cp ^ (row & 7);
            gload_lds16(Vtt + (size_t)row * 2048 + gc * 8, &Vs[buf][slot * 8]);
        }
    };

    // ---- load Q rows for both q-tiles straight from qkv, RoPE in registers
    bf16x8 qa[4], qb[4];
#pragma unroll
    for (int which = 0; which < 2; ++which) {
        const int qt = which ? qtB : qtA;
        const int s  = qt * 64 + w * 16 + m;
        bf16x8 raw[4];
        const u16* qp = qkv + (size_t)s * 6144 + h * 128 + quad * 8;
#pragma unroll
        for (int kk = 0; kk < 4; ++kk)
            raw[kk] = *(const bf16x8*)(qp + kk * 32);
        bf16x8* dst = which ? qb : qa;
#pragma unroll
        for (int half = 0; half < 2; ++half)
#pragma unroll
            for (int j = 0; j < 8; ++j) {
                int d = half * 32 + quad * 8 + j;
                float inv = __expf(-(float)d * (9.210340371976184f / 64.0f));
                float ang = (float)s * inv;
                float cs, sn; __sincosf(ang, &sn, &cs);
                float x1 = bf2f(((const u16*)&raw[half])[j]);
                float x2 = bf2f(((const u16*)&raw[half + 2])[j]);
                ((u16*)&dst[half])[j]     = f2bf(x1 * cs - x2 * sn);
                ((u16*)&dst[half + 2])[j] = f2bf(x1 * sn + x2 * cs);
            }
    }

    f32x4 accA[8], accB[8];
#pragma unroll
    for (int i = 0; i < 8; ++i) { accA[i] = f32x4{0.f, 0.f, 0.f, 0.f}; accB[i] = f32x4{0.f, 0.f, 0.f, 0.f}; }
    float lA = 0.f, lB = 0.f;

    stage(0, 0);
    for (int kt = 0; kt <= qtB; ++kt) {
        __syncthreads();                       // drains *previous* prefetch only
        if (kt < qtB) stage((kt + 1) & 1, kt + 1);   // fly during this tile's math

        const u16* ks = Ks[kt & 1];
        const u16* vs = Vs[kt & 1];
        if (kt <= qtA)
            attn_pass2<true >(qa, qb, accA, accB, lA, lB, ks, vs, w, m, quad,
                              kt == qtA, false, sl2e);
        else
            attn_pass2<false>(qa, qb, accA, accB, lA, lB, ks, vs, w, m, quad,
                              false, kt == qtB, sl2e);
    }

    // ---- epilogues
#pragma unroll
    for (int which = 0; which < 2; ++which) {
        const int qt  = which ? qtB : qtA;
        f32x4*   acc  = which ? accB : accA;
        float    l    = which ? lB   : lA;
        l += __shfl_xor(l, 16);
        l += __shfl_xor(l, 32);
        float linv[4];
#pragma unroll
        for (int r = 0; r < 4; ++r)
            linv[r] = 1.f / __shfl(l, quad * 4 + r);
#pragma unroll
        for (int r = 0; r < 4; ++r) {
            size_t rowg = (size_t)(qt * 64 + w * 16 + quad * 4 + r);
#pragma unroll
            for (int nt = 0; nt < 8; ++nt)
                ctx[rowg * 4096 + h * 128 + nt * 16 + m] = f2bf(acc[nt][r] * linv[r]);
        }
    }
}

// ---------------------------------------------------------------------------
// Launcher
// ---------------------------------------------------------------------------
extern "C" void kernel_launch(void* const* d_in, const int* in_sizes, int n_in,
                              void* d_out, int out_size, void* d_ws, size_t ws_size,
                              hipStream_t stream) {
    const float* hs   = (const float*)d_in[0];   // (1,2048,4096)
    const float* wqkv = (const float*)d_in[1];   // (6144,4096)
    const float* wo   = (const float*)d_in[2];   // (4096,4096)
    float* out = (float*)d_out;                  // (1,2048,4096) fp32

    char* ws = (char*)d_ws;
    u16* hA  = (u16*)ws;  ws += (size_t)2048 * 4096 * 2;   // hidden bf16
    u16* wQ  = (u16*)ws;  ws += (size_t)6144 * 4096 * 2;   // Wqkv bf16
    u16* wO  = (u16*)ws;  ws += (size_t)4096 * 4096 * 2;   // Wo bf16
    u16* qkv = (u16*)ws;  ws += (size_t)2048 * 6144 * 2;   // qkv bf16
    u16* Kb  = (u16*)ws;  ws += (size_t)8 * 2048 * 128 * 2; // K, RoPE'd
    u16* Vt  = (u16*)ws;  ws += (size_t)8 * 128 * 2048 * 2; // V transposed
    u16* ctx = (u16*)ws;  ws += (size_t)2048 * 4096 * 2;   // attention output

    // all three fp32->bf16 conversions in one launch
    cvt_all<<<49152, 256, 0, stream>>>((const float4*)hs,   (uint2*)hA,
                                       (const float4*)wqkv, (uint2*)wQ,
                                       (const float4*)wo,   (uint2*)wO);

    // qkv = hidden @ Wqkv^T   (M=2048, N=6144, K=4096): 192 blocks (8x24)
    gemm_bt8<u16><<<192, 512, 0, stream>>>(hA, wQ, qkv, 2048, 6144, 4096);

    // K RoPE + V transpose in one launch
    prep_kv<<<5120, 256, 0, stream>>>(qkv, Kb, Vt);

    // balanced, merged-pass, register-P flash attention
    attn_mfma<<<dim3(16, 32), 256, 0, stream>>>(qkv, Kb, Vt, ctx);

    // out = ctx @ Wo^T   (M=2048, N=4096, K=4096): 128 blocks (8x16)
    gemm_bt8<float><<<128, 512, 0, stream>>>(ctx, wO, out, 2048, 4096, 4096);
}